// Round 13
// baseline (504.451 us; speedup 1.0000x reference)
//
#include <hip/hip_runtime.h>
#include <hip/hip_fp16.h>

// Hankel MPS, round 18: B_T=64 with combine race FIXED.
//
// Round-12 post-mortem: r17 failed absmax (4.25e-22): the eq0 combine
// interleaved slot reads and vsum writes over the SAME aliased LDS —
// bh0's vsum write (bytes <8448 for rh0) clobbered slot rh*2+1 before
// bh1 read it. Fix: ALL slot reads into vn0/vn1 BEFORE any vsum write.
// Per-accumulator add order unchanged -> absmax must return to the
// bit-identical 1.654361e-24.
//
// Design (r17): 128 blocks x 512 thr, B_T=64. Each block reads the same
// 2MB/step H slice but does 2x MFMA (H frags shared by both 32-b tiles):
// per-XCD L2 demand 28.4 -> 14.2us/step; MFMA 20.6us/step -> MFMA-bound.
//
// ws: encH 25.17M | HmH 10.49M | HmL 10.49M | w1f 64K | w2f 128K  (46.3 MB)

#define B_ALL 8192
#define TT    12
#define B_T   64     // trajectories per block
#define NBLK  128    // 8192 / 64

typedef short bfrag __attribute__((ext_vector_type(8)));      // 8 bf16
typedef _Float16 hfrag __attribute__((ext_vector_type(8)));   // 8 fp16
typedef float ffrag __attribute__((ext_vector_type(16)));     // 32x32 C/D

#define O_ENC   0ULL
#define O_HMH   25165824ULL
#define O_HML   35651584ULL
#define O_W1F   46137344ULL
#define O_W2F   46202880ULL

__device__ __forceinline__ unsigned short bf16_rne(float f) {
    unsigned int u = __builtin_bit_cast(unsigned int, f);
    unsigned int r = (u + 0x7fffu + ((u >> 16) & 1u)) >> 16;
    return (unsigned short)r;
}
__device__ __forceinline__ float bf16_f32(unsigned short h) {
    unsigned int u = ((unsigned int)h) << 16;
    return __builtin_bit_cast(float, u);
}

// ---------------- prep: coalesced H conversion + W frag-order (verified) ----------------
__global__ __launch_bounds__(256)
void prep_kernel(const float* __restrict__ W1, const float* __restrict__ W2,
                 const float* __restrict__ Hm,
                 __half* __restrict__ w1f, __half* __restrict__ w2f,
                 unsigned short* __restrict__ Hh, unsigned short* __restrict__ Hl)
{
    const int tid = threadIdx.x;
    const int bid = blockIdx.x;
    if (bid < 1280) {
        __shared__ unsigned short hs[4096], ls[4096];
        const int t = bid >> 7, e = bid & 127;
        const float* src = Hm + ((size_t)t * 64 * 128 + e) * 64;   // + p*8192 + r
        const int p  = tid >> 2;
        const int rc = (tid & 3) * 16;
        const int fp = (p >> 4) * 512 + ((p >> 3) & 1) * 256 + (p & 7); // p part of f
        #pragma unroll
        for (int k4 = 0; k4 < 4; ++k4) {
            const int r0 = rc + k4 * 4;
            const float4 v4 = *(const float4*)&src[(size_t)p * 8192 + r0];
            const float vv[4] = {v4.x, v4.y, v4.z, v4.w};
            #pragma unroll
            for (int k = 0; k < 4; ++k) {
                const int r = r0 + k;
                const int f = (r >> 5) * 2048 + (r & 31) * 8 + fp;
                const float val = vv[k];
                const unsigned short hi = bf16_rne(val);
                const unsigned short lo = bf16_rne(val - bf16_f32(hi));
                hs[f] = hi;
                ls[f] = lo;
            }
        }
        __syncthreads();
        const size_t q0 = (size_t)t * 524288 + (size_t)e * 4096 + tid * 16;
        *(uint4*)&Hh[q0]     = *(const uint4*)&hs[tid * 16];
        *(uint4*)&Hh[q0 + 8] = *(const uint4*)&hs[tid * 16 + 8];
        *(uint4*)&Hl[q0]     = *(const uint4*)&ls[tid * 16];
        *(uint4*)&Hl[q0 + 8] = *(const uint4*)&ls[tid * 16 + 8];
    } else {
        const int wb = bid - 1280;
        const long long N_W1 = 32768, N_W2 = 65536;
        for (long long idx = wb * 256 + tid; idx < N_W1 + N_W2; idx += 8 * 256) {
            if (idx < N_W1) {
                const int w = (int)idx;
                const int jn = w >> 11, ks = (w >> 9) & 3, half = (w >> 8) & 1;
                const int jl = (w >> 3) & 31, jj = w & 7;
                const int j = jn * 32 + jl, d = ks * 16 + half * 8 + jj;
                w1f[w] = __float2half(W1[j * 64 + d]);
            } else {
                const int w = (int)(idx - N_W1);
                const int en = w >> 14, ks2g = (w >> 9) & 31, half = (w >> 8) & 1;
                const int el = (w >> 3) & 31, jj = w & 7;
                const int e = en * 32 + el, j = ks2g * 16 + half * 8 + jj;
                w2f[w] = __float2half(W2[e * 512 + j]);
            }
        }
    }
}

// ---------------- encoder (verified standalone) ----------------
__global__ __launch_bounds__(256)
void enc_kernel(const float* __restrict__ x,
                const float* __restrict__ b1, const float* __restrict__ b2,
                const __half* __restrict__ w1f, const __half* __restrict__ w2f,
                __half* __restrict__ encH)
{
    __shared__ __align__(16) unsigned char smem[17408];
    float* x_s  = (float*)smem;
    __half* h_s = (__half*)smem;

    const int tid   = threadIdx.x;
    const int wv    = tid >> 6;
    const int lane  = tid & 63;
    const int l32   = lane & 31;
    const int half  = lane >> 5;
    const int msub  = wv >> 1;
    const int nhalf = wv & 1;
    const int m0    = blockIdx.x * 64;

    #pragma unroll
    for (int i = 0; i < 4; ++i) {
        const int f4 = i * 256 + tid;
        const int r = f4 >> 4, c4 = (f4 & 15) * 4;
        *(float4*)&x_s[r * 68 + c4] =
            *(const float4*)&x[(long long)(m0 + r) * 64 + c4];
    }
    __syncthreads();

    hfrag xa[4];
    #pragma unroll
    for (int ks = 0; ks < 4; ++ks) {
        const float* src = &x_s[(msub * 32 + l32) * 68 + ks * 16 + half * 8];
        const float4 a = *(const float4*)src;
        const float4 b = *(const float4*)(src + 4);
        hfrag v;
        v[0] = (_Float16)a.x; v[1] = (_Float16)a.y;
        v[2] = (_Float16)a.z; v[3] = (_Float16)a.w;
        v[4] = (_Float16)b.x; v[5] = (_Float16)b.y;
        v[6] = (_Float16)b.z; v[7] = (_Float16)b.w;
        xa[ks] = v;
    }
    __syncthreads();

    ffrag c2[2];
    c2[0] = 0.0f; c2[1] = 0.0f;

    for (int chunk = 0; chunk < 4; ++chunk) {
        ffrag c1[2];
        float b1j[2];
        #pragma unroll
        for (int nf = 0; nf < 2; ++nf) {
            const int jn = chunk * 4 + nhalf * 2 + nf;
            b1j[nf] = b1[jn * 32 + l32];
            ffrag acc = 0.0f;
            #pragma unroll
            for (int ks = 0; ks < 4; ++ks) {
                const hfrag bh = *(const hfrag*)(w1f + (jn * 4 + ks) * 512
                                                 + half * 256 + l32 * 8);
                acc = __builtin_amdgcn_mfma_f32_32x32x16_f16(xa[ks], bh, acc, 0, 0, 0);
            }
            c1[nf] = acc;
        }
        __syncthreads();
        #pragma unroll
        for (int nf = 0; nf < 2; ++nf) {
            #pragma unroll
            for (int i2 = 0; i2 < 16; ++i2) {
                const int m_row = (i2 & 3) + 8 * (i2 >> 2) + 4 * half;
                const float v = fmaxf(c1[nf][i2] + b1j[nf], 0.0f);
                h_s[(msub * 32 + m_row) * 136 + nhalf * 64 + nf * 32 + l32] =
                    __float2half(v);
            }
        }
        __syncthreads();
        #pragma unroll
        for (int ks2 = 0; ks2 < 8; ++ks2) {
            const hfrag a = *(const hfrag*)&h_s[(msub * 32 + l32) * 136
                                                + ks2 * 16 + half * 8];
            const int ks2g = chunk * 8 + ks2;
            #pragma unroll
            for (int ef = 0; ef < 2; ++ef) {
                const int en = nhalf * 2 + ef;
                const hfrag b = *(const hfrag*)(w2f + (en * 32 + ks2g) * 512
                                                + half * 256 + l32 * 8);
                c2[ef] = __builtin_amdgcn_mfma_f32_32x32x16_f16(a, b, c2[ef], 0, 0, 0);
            }
        }
    }

    #pragma unroll
    for (int ef = 0; ef < 2; ++ef) {
        const int e = nhalf * 64 + ef * 32 + l32;
        const float b2e = b2[e];
        #pragma unroll
        for (int i2 = 0; i2 < 16; ++i2) {
            const int m_row = (i2 & 3) + 8 * (i2 >> 2) + 4 * half;
            const int m_g = m0 + msub * 32 + m_row;
            encH[(long long)m_g * 128 + e] =
                __float2half(fmaxf(c2[ef][i2] + b2e, 0.0f));
        }
    }
}

// ---------------- full chain: B_T=64, 128 blocks x 512 thr ----------------
// Waves: eq = wv>>1 (e-quarter, 32 e), rh = wv&1 (r-half). Each wave computes
// its 32 r x 64 b (2 b-tiles sharing the same H A-frags) over its e-quarter.
//
// LDS map (52800 B):
//   vsum  @ 0      : [64 p][66] f32  = 16896
//   enc_s @ 16896  : [128 e][66] f32 = 33792   (ends 50688)
//   scr   @ 0      : 12 slots x 4 float4-rows, stride 66 (aliases vsum+enc_s,
//                    both dead at combine; per-rh write regions disjoint;
//                    within-wave: ALL reads before ANY write — r17 bugfix)
//   red   @ 50688  : [8][66] f32 = 2112        (final)
__global__ __launch_bounds__(512, 1)
void chain_all(const unsigned short* __restrict__ HmH,
               const unsigned short* __restrict__ HmL,
               const __half* __restrict__ encH,
               const float* __restrict__ Hf,
               const float* __restrict__ HL,
               float* __restrict__ out)
{
    __shared__ __align__(16) unsigned char smem[52800];
    float* vsum  = (float*)smem;
    float* enc_s = (float*)(smem + 16896);
    float* red   = (float*)(smem + 50688);

    const int tid  = threadIdx.x;
    const int b0   = blockIdx.x * B_T;
    const int lane = tid & 63;
    const int wv   = tid >> 6;
    const int l32  = lane & 31;
    const int half = lane >> 5;
    const int eq   = wv >> 1;      // 0..3  (e-quarter)
    const int rh   = wv & 1;       // 0..1  (r-half)

    // enc staging: [128 e][64 b] f32 for one timestep (all 512 threads)
    const int sbL = tid >> 3;            // 0..63 (b-local)
    const int seo = (tid & 7) * 16;      // 0..112 (e-offset)
    #define STAGE_ENC(T)                                                        \
    {                                                                           \
        const __half* er_ = encH + ((size_t)(b0 + sbL) * 12 + (T)) * 128 + seo; \
        uint4 u0_ = *(const uint4*)er_;                                         \
        uint4 u1_ = *(const uint4*)(er_ + 8);                                   \
        const __half* hp_ = (const __half*)&u0_;                                \
        const __half* hq_ = (const __half*)&u1_;                                \
        _Pragma("unroll")                                                       \
        for (int j = 0; j < 8; ++j)                                             \
            enc_s[(seo + j) * 66 + sbL] = __half2float(hp_[j]);                 \
        _Pragma("unroll")                                                       \
        for (int j = 0; j < 8; ++j)                                             \
            enc_s[(seo + 8 + j) * 66 + sbL] = __half2float(hq_[j]);             \
    }

    // ---- init: v0[p][b] = sum_e enc(b,0,e) * Hf[e][p] ----
    {
        STAGE_ENC(0);
        __syncthreads();
        const int pg = tid >> 6, bI = tid & 63;   // pg 0..7 (8 p each)
        float acc[8] = {0, 0, 0, 0, 0, 0, 0, 0};
        for (int e = 0; e < 128; ++e) {
            const float ev = enc_s[e * 66 + bI];
            const float4 h0 = *(const float4*)&Hf[e * 64 + pg * 8];     // wave-uniform
            const float4 h1 = *(const float4*)&Hf[e * 64 + pg * 8 + 4];
            acc[0] += ev * h0.x; acc[1] += ev * h0.y;
            acc[2] += ev * h0.z; acc[3] += ev * h0.w;
            acc[4] += ev * h1.x; acc[5] += ev * h1.y;
            acc[6] += ev * h1.z; acc[7] += ev * h1.w;
        }
        #pragma unroll
        for (int i = 0; i < 8; ++i)
            vsum[(pg * 8 + i) * 66 + bI] = acc[i];
        __syncthreads();
    }

    // ---- chain: 10 steps, all in-block ----
    const unsigned short* Hsh = HmH;
    const unsigned short* Hsl = HmL;
    const int lanoff = rh * 2048 + half * 256 + l32 * 8;

    #pragma unroll 1
    for (int t = 1; t <= 10; ++t) {
        STAGE_ENC(t);

        // B-frags: v hi/lo split from vsum for BOTH 32-b column tiles
        bfrag vbh[2][4], vbl[2][4];
        #pragma unroll
        for (int bh = 0; bh < 2; ++bh) {
            #pragma unroll
            for (int s = 0; s < 4; ++s) {
                const int p0 = s * 16 + half * 8;
                bfrag hb, lb;
                #pragma unroll
                for (int j = 0; j < 8; ++j) {
                    const float f = vsum[(p0 + j) * 66 + bh * 32 + l32];
                    const unsigned short hi = bf16_rne(f);
                    const unsigned short lo = bf16_rne(f - bf16_f32(hi));
                    hb[j] = (short)hi;
                    lb[j] = (short)lo;
                }
                vbh[bh][s] = hb;
                vbl[bh][s] = lb;
            }
        }
        __syncthreads();   // enc_s staged; vsum reads complete

        // e-loop: 32-e quarter, depth-1 ping-pong prefetch; H frags shared
        // by both b-tiles (2x MFMA per load vs B_T=32).
        const unsigned short* hp = Hsh + (size_t)(eq * 32) * 4096 + lanoff;
        const unsigned short* lp = Hsl + (size_t)(eq * 32) * 4096 + lanoff;
        bfrag cah[4], cal[4];
        #pragma unroll
        for (int s = 0; s < 4; ++s) {
            cah[s] = *(const bfrag*)(hp + s * 512);
            cal[s] = *(const bfrag*)(lp + s * 512);
        }
        ffrag z = 0.0f;
        ffrag vn0 = 0.0f, vn1 = 0.0f;
        #pragma unroll 2
        for (int e = 0; e < 32; ++e) {
            hp += 4096; lp += 4096;
            bfrag nah[4], nal[4];   // last iter reads <=8KB past slice (allocated ws)
            #pragma unroll
            for (int s = 0; s < 4; ++s) {
                nah[s] = *(const bfrag*)(hp + s * 512);
                nal[s] = *(const bfrag*)(lp + s * 512);
            }
            const float ev0 = enc_s[(eq * 32 + e) * 66 + l32];
            const float ev1 = enc_s[(eq * 32 + e) * 66 + 32 + l32];
            ffrag w0 = z, w1 = z;
            #pragma unroll
            for (int s = 0; s < 4; ++s) {
                w0 = __builtin_amdgcn_mfma_f32_32x32x16_bf16(cah[s], vbh[0][s], w0, 0, 0, 0);
                w1 = __builtin_amdgcn_mfma_f32_32x32x16_bf16(cah[s], vbh[1][s], w1, 0, 0, 0);
                w0 = __builtin_amdgcn_mfma_f32_32x32x16_bf16(cah[s], vbl[0][s], w0, 0, 0, 0);
                w1 = __builtin_amdgcn_mfma_f32_32x32x16_bf16(cah[s], vbl[1][s], w1, 0, 0, 0);
                w0 = __builtin_amdgcn_mfma_f32_32x32x16_bf16(cal[s], vbh[0][s], w0, 0, 0, 0);
                w1 = __builtin_amdgcn_mfma_f32_32x32x16_bf16(cal[s], vbh[1][s], w1, 0, 0, 0);
            }
            vn0 += w0 * ev0;
            vn1 += w1 * ev1;
            #pragma unroll
            for (int s = 0; s < 4; ++s) { cah[s] = nah[s]; cal[s] = nal[s]; }
        }
        __syncthreads();   // e-loop LDS reads done; vsum+enc_s region = scratch

        // cross-eq combine: 12 slots (3 eq-groups x 2 rh x 2 bh), stride-66
        // float4 rows over the full scratch. Writers: eq1..3. Reader: eq0,
        // ascending g per accumulator (same add order as B_T=32 version).
        float4* sc4 = (float4*)smem;
        if (eq != 0) {
            #pragma unroll
            for (int bh = 0; bh < 2; ++bh) {
                const ffrag vv = bh ? vn1 : vn0;
                const int slot = (eq - 1) * 4 + rh * 2 + bh;
                #pragma unroll
                for (int q = 0; q < 4; ++q) {
                    float4 f4 = {vv[q * 4 + 0], vv[q * 4 + 1],
                                 vv[q * 4 + 2], vv[q * 4 + 3]};
                    sc4[(slot * 4 + q) * 66 + lane] = f4;
                }
            }
        }
        __syncthreads();
        if (eq == 0) {
            // r17 BUGFIX: complete ALL slot reads (both bh, all g) into the
            // named accumulators BEFORE any vsum write — the vsum rows for
            // this rh alias this rh's own slots.
            #pragma unroll
            for (int g = 1; g < 4; ++g) {
                const int s0 = (g - 1) * 4 + rh * 2;       // bh0 slot
                #pragma unroll
                for (int q = 0; q < 4; ++q) {
                    const float4 f0 = sc4[(s0 * 4 + q) * 66 + lane];
                    const float4 f1 = sc4[((s0 + 1) * 4 + q) * 66 + lane];
                    vn0[q * 4 + 0] += f0.x; vn0[q * 4 + 1] += f0.y;
                    vn0[q * 4 + 2] += f0.z; vn0[q * 4 + 3] += f0.w;
                    vn1[q * 4 + 0] += f1.x; vn1[q * 4 + 1] += f1.y;
                    vn1[q * 4 + 2] += f1.z; vn1[q * 4 + 3] += f1.w;
                }
            }
            #pragma unroll
            for (int i = 0; i < 16; ++i) {
                const int r = rh * 32 + (i & 3) + 8 * (i >> 2) + 4 * half;
                vsum[r * 66 + l32]      = vn0[i];
                vsum[r * 66 + 32 + l32] = vn1[i];
            }
        }
        __syncthreads();   // vsum ready for next step

        Hsh += 524288;
        Hsl += 524288;
    }

    // ---- final: out[b] = sum_p v[p][b] * (sum_e enc(b,11,e) * HL[p][e]) ----
    {
        STAGE_ENC(11);
        __syncthreads();
        const int pg = tid >> 6, bI = tid & 63;   // pg 0..7, 8 p each
        float s = 0.0f;
        #pragma unroll
        for (int i = 0; i < 8; ++i) {
            const int p = pg * 8 + i;
            float L = 0.0f;
            #pragma unroll 16
            for (int e = 0; e < 128; ++e)
                L += enc_s[e * 66 + bI] * HL[p * 128 + e];   // HL row L1-broadcast
            s += vsum[p * 66 + bI] * L;
        }
        red[pg * 66 + bI] = s;
        __syncthreads();
        if (tid < 64) {
            float acc = 0.0f;
            #pragma unroll
            for (int g = 0; g < 8; ++g)
                acc += red[g * 66 + tid];
            out[b0 + tid] = acc;
        }
    }
    #undef STAGE_ENC
}

extern "C" void kernel_launch(void* const* d_in, const int* in_sizes, int n_in,
                              void* d_out, int out_size, void* d_ws, size_t ws_size,
                              hipStream_t stream) {
    const float* x  = (const float*)d_in[0];
    const float* W1 = (const float*)d_in[1];
    const float* b1 = (const float*)d_in[2];
    const float* W2 = (const float*)d_in[3];
    const float* b2 = (const float*)d_in[4];
    const float* Hf = (const float*)d_in[5];
    const float* Hm = (const float*)d_in[6];
    const float* HL = (const float*)d_in[7];
    float* out = (float*)d_out;
    (void)in_sizes; (void)n_in; (void)out_size; (void)ws_size;

    char* ws = (char*)d_ws;
    __half* encH        = (__half*)(ws + O_ENC);
    unsigned short* HmH = (unsigned short*)(ws + O_HMH);
    unsigned short* HmL = (unsigned short*)(ws + O_HML);
    __half* w1f         = (__half*)(ws + O_W1F);
    __half* w2f         = (__half*)(ws + O_W2F);

    prep_kernel<<<dim3(1288), dim3(256), 0, stream>>>(W1, W2, Hm, w1f, w2f, HmH, HmL);
    enc_kernel<<<dim3(1536), dim3(256), 0, stream>>>(x, b1, b2, w1f, w2f, encH);
    chain_all<<<dim3(NBLK), dim3(512), 0, stream>>>(HmH, HmL, encH, Hf, HL, out);
}

// Round 14
// 408.171 us; speedup vs baseline: 1.2359x; 1.2359x over previous
//
#include <hip/hip_runtime.h>
#include <hip/hip_fp16.h>

// Hankel MPS, round 19: r12 chain (3x-verified 287us) + enc∥H-convert fusion.
//
// Round-13 post-mortem: B_T=64 = 128 blocks on 256 CUs -> half the chip idle
// (Occupancy 11.4%); busy CUs 40us/step. Branch closed. Chain reverted to the
// verified 256-block r12 form (287us = per-XCD L2 fabric roofline).
//
// Round-19: enc (needs only w1f/w2f) and H-conversion (needs nothing from
// enc) are independent -> run them as disjoint block ranges of ONE kernel:
//   prep_w   (384 blk): W1/W2 -> fp16 frag order (~3us)
//   enc_conv (2816 blk): blocks 0..1535 = enc verbatim;
//                        1536..2815 = per-(t,e) H slice convert verbatim
//   chain_all (256 blk): r12 verbatim
// Pure reorganization of verified code -> absmax bit-identical 1.654361e-24.
//
// ws: encH 25.17M | HmH 10.49M | HmL 10.49M | w1f 64K | w2f 128K  (46.3 MB)

#define B_ALL 8192
#define TT    12
#define B_T   32     // trajectories per block (chain)
#define NBLK  256    // 8192 / 32

typedef short bfrag __attribute__((ext_vector_type(8)));      // 8 bf16
typedef _Float16 hfrag __attribute__((ext_vector_type(8)));   // 8 fp16
typedef float ffrag __attribute__((ext_vector_type(16)));     // 32x32 C/D

#define O_ENC   0ULL
#define O_HMH   25165824ULL
#define O_HML   35651584ULL
#define O_W1F   46137344ULL
#define O_W2F   46202880ULL

__device__ __forceinline__ unsigned short bf16_rne(float f) {
    unsigned int u = __builtin_bit_cast(unsigned int, f);
    unsigned int r = (u + 0x7fffu + ((u >> 16) & 1u)) >> 16;
    return (unsigned short)r;
}
__device__ __forceinline__ float bf16_f32(unsigned short h) {
    unsigned int u = ((unsigned int)h) << 16;
    return __builtin_bit_cast(float, u);
}

// ---------------- prep_w: W1/W2 -> fp16 frag order (tiny) ----------------
// grid 384 x 256: one element per thread (98304 total).
__global__ __launch_bounds__(256)
void prep_w(const float* __restrict__ W1, const float* __restrict__ W2,
            __half* __restrict__ w1f, __half* __restrict__ w2f)
{
    const int idx = blockIdx.x * 256 + threadIdx.x;
    if (idx < 32768) {
        const int w = idx;
        const int jn = w >> 11, ks = (w >> 9) & 3, half = (w >> 8) & 1;
        const int jl = (w >> 3) & 31, jj = w & 7;
        const int j = jn * 32 + jl, d = ks * 16 + half * 8 + jj;
        w1f[w] = __float2half(W1[j * 64 + d]);
    } else {
        const int w = idx - 32768;
        const int en = w >> 14, ks2g = (w >> 9) & 31, half = (w >> 8) & 1;
        const int el = (w >> 3) & 31, jj = w & 7;
        const int e = en * 32 + el, j = ks2g * 16 + half * 8 + jj;
        w2f[w] = __float2half(W2[e * 512 + j]);
    }
}

// ---------------- enc_conv: enc (blocks 0..1535) ∥ H-convert (1536..2815) ----------------
__global__ __launch_bounds__(256)
void enc_conv(const float* __restrict__ x,
              const float* __restrict__ b1, const float* __restrict__ b2,
              const __half* __restrict__ w1f, const __half* __restrict__ w2f,
              __half* __restrict__ encH,
              const float* __restrict__ Hm,
              unsigned short* __restrict__ Hh, unsigned short* __restrict__ Hl)
{
    __shared__ __align__(16) unsigned char smem[17408];
    const int tid = threadIdx.x;
    const int bid = blockIdx.x;

    if (bid >= 1536) {
        // ---- H-convert: one 64p x 64r slice (r15-verified, bid shifted) ----
        unsigned short* hs = (unsigned short*)smem;
        unsigned short* ls = (unsigned short*)(smem + 8192);
        const int hb = bid - 1536;
        const int t = hb >> 7, e = hb & 127;
        const float* src = Hm + ((size_t)t * 64 * 128 + e) * 64;   // + p*8192 + r
        const int p  = tid >> 2;
        const int rc = (tid & 3) * 16;
        const int fp = (p >> 4) * 512 + ((p >> 3) & 1) * 256 + (p & 7); // p part of f
        #pragma unroll
        for (int k4 = 0; k4 < 4; ++k4) {
            const int r0 = rc + k4 * 4;
            const float4 v4 = *(const float4*)&src[(size_t)p * 8192 + r0];
            const float vv[4] = {v4.x, v4.y, v4.z, v4.w};
            #pragma unroll
            for (int k = 0; k < 4; ++k) {
                const int r = r0 + k;
                const int f = (r >> 5) * 2048 + (r & 31) * 8 + fp;
                const float val = vv[k];
                const unsigned short hi = bf16_rne(val);
                const unsigned short lo = bf16_rne(val - bf16_f32(hi));
                hs[f] = hi;
                ls[f] = lo;
            }
        }
        __syncthreads();
        const size_t q0 = (size_t)t * 524288 + (size_t)e * 4096 + tid * 16;
        *(uint4*)&Hh[q0]     = *(const uint4*)&hs[tid * 16];
        *(uint4*)&Hh[q0 + 8] = *(const uint4*)&hs[tid * 16 + 8];
        *(uint4*)&Hl[q0]     = *(const uint4*)&ls[tid * 16];
        *(uint4*)&Hl[q0 + 8] = *(const uint4*)&ls[tid * 16 + 8];
        return;
    }

    // ---- enc (verbatim r15) ----
    float* x_s  = (float*)smem;
    __half* h_s = (__half*)smem;

    const int wv    = tid >> 6;
    const int lane  = tid & 63;
    const int l32   = lane & 31;
    const int half  = lane >> 5;
    const int msub  = wv >> 1;
    const int nhalf = wv & 1;
    const int m0    = bid * 64;

    #pragma unroll
    for (int i = 0; i < 4; ++i) {
        const int f4 = i * 256 + tid;
        const int r = f4 >> 4, c4 = (f4 & 15) * 4;
        *(float4*)&x_s[r * 68 + c4] =
            *(const float4*)&x[(long long)(m0 + r) * 64 + c4];
    }
    __syncthreads();

    hfrag xa[4];
    #pragma unroll
    for (int ks = 0; ks < 4; ++ks) {
        const float* src = &x_s[(msub * 32 + l32) * 68 + ks * 16 + half * 8];
        const float4 a = *(const float4*)src;
        const float4 b = *(const float4*)(src + 4);
        hfrag v;
        v[0] = (_Float16)a.x; v[1] = (_Float16)a.y;
        v[2] = (_Float16)a.z; v[3] = (_Float16)a.w;
        v[4] = (_Float16)b.x; v[5] = (_Float16)b.y;
        v[6] = (_Float16)b.z; v[7] = (_Float16)b.w;
        xa[ks] = v;
    }
    __syncthreads();

    ffrag c2[2];
    c2[0] = 0.0f; c2[1] = 0.0f;

    for (int chunk = 0; chunk < 4; ++chunk) {
        ffrag c1[2];
        float b1j[2];
        #pragma unroll
        for (int nf = 0; nf < 2; ++nf) {
            const int jn = chunk * 4 + nhalf * 2 + nf;
            b1j[nf] = b1[jn * 32 + l32];
            ffrag acc = 0.0f;
            #pragma unroll
            for (int ks = 0; ks < 4; ++ks) {
                const hfrag bh = *(const hfrag*)(w1f + (jn * 4 + ks) * 512
                                                 + half * 256 + l32 * 8);
                acc = __builtin_amdgcn_mfma_f32_32x32x16_f16(xa[ks], bh, acc, 0, 0, 0);
            }
            c1[nf] = acc;
        }
        __syncthreads();
        #pragma unroll
        for (int nf = 0; nf < 2; ++nf) {
            #pragma unroll
            for (int i2 = 0; i2 < 16; ++i2) {
                const int m_row = (i2 & 3) + 8 * (i2 >> 2) + 4 * half;
                const float v = fmaxf(c1[nf][i2] + b1j[nf], 0.0f);
                h_s[(msub * 32 + m_row) * 136 + nhalf * 64 + nf * 32 + l32] =
                    __float2half(v);
            }
        }
        __syncthreads();
        #pragma unroll
        for (int ks2 = 0; ks2 < 8; ++ks2) {
            const hfrag a = *(const hfrag*)&h_s[(msub * 32 + l32) * 136
                                                + ks2 * 16 + half * 8];
            const int ks2g = chunk * 8 + ks2;
            #pragma unroll
            for (int ef = 0; ef < 2; ++ef) {
                const int en = nhalf * 2 + ef;
                const hfrag b = *(const hfrag*)(w2f + (en * 32 + ks2g) * 512
                                                + half * 256 + l32 * 8);
                c2[ef] = __builtin_amdgcn_mfma_f32_32x32x16_f16(a, b, c2[ef], 0, 0, 0);
            }
        }
    }

    #pragma unroll
    for (int ef = 0; ef < 2; ++ef) {
        const int e = nhalf * 64 + ef * 32 + l32;
        const float b2e = b2[e];
        #pragma unroll
        for (int i2 = 0; i2 < 16; ++i2) {
            const int m_row = (i2 & 3) + 8 * (i2 >> 2) + 4 * half;
            const int m_g = m0 + msub * 32 + m_row;
            encH[(long long)m_g * 128 + e] =
                __float2half(fmaxf(c2[ef][i2] + b2e, 0.0f));
        }
    }
}

// ---------------- full chain (r12, 3x-verified 287us) ----------------
// 256 blocks x 512 thr (1 block/CU). Block owns b0..b0+31. 8 waves:
// eq = wv>>1 (e-quarter, 32 e), rh = wv&1 (r-half). v lives in LDS across
// all steps. e-loop software-pipelined: prefetch e+1 frags before e's MFMAs.
//
// LDS map (60480 B):
//   vsum  @ 0      : [64][33] f32                  = 8448
//   enc_s @ 8448   : [128][33] f32 (one timestep)  = 16896
//   scr   @ 25344  : stride-66 float4 combine      (chain)
//   hl_s  @ 25344  : [64][129] f32                 (final, scr dead)
//   red   @ 58368  : [16][33] f32                  (final)
__global__ __launch_bounds__(512, 1)
void chain_all(const unsigned short* __restrict__ HmH,
               const unsigned short* __restrict__ HmL,
               const __half* __restrict__ encH,
               const float* __restrict__ Hf,
               const float* __restrict__ HL,
               float* __restrict__ out)
{
    __shared__ __align__(16) unsigned char smem[60480];
    float* vsum  = (float*)smem;
    float* enc_s = (float*)(smem + 8448);
    float* scr   = (float*)(smem + 25344);
    float* hl_s  = (float*)(smem + 25344);
    float* red   = (float*)(smem + 58368);

    const int tid  = threadIdx.x;
    const int b0   = blockIdx.x * B_T;
    const int lane = tid & 63;
    const int wv   = tid >> 6;
    const int l32  = lane & 31;
    const int half = lane >> 5;
    const int eq   = wv >> 1;      // 0..3  (e-quarter)
    const int rh   = wv & 1;       // 0..1  (r-half)

    // enc staging: [128 e][32 b] f32 for one timestep (all 512 threads)
    const int sbL = tid >> 4;            // 0..31 (b-local)
    const int seo = (tid & 15) * 8;      // 0..120 (e-offset)
    #define STAGE_ENC(T)                                                      \
    {                                                                         \
        const __half* er_ = encH + ((size_t)(b0 + sbL) * 12 + (T)) * 128 + seo;\
        uint4 u = *(const uint4*)er_;                                         \
        const __half* hp_ = (const __half*)&u;                                \
        _Pragma("unroll")                                                     \
        for (int j = 0; j < 8; ++j)                                           \
            enc_s[(seo + j) * 33 + sbL] = __half2float(hp_[j]);               \
    }

    // ---- init: v0[p][b] = sum_e enc(b,0,e) * Hf[e][p] ----
    {
        STAGE_ENC(0);
        __syncthreads();
        const int bI = tid & 31, pg = tid >> 5;   // pg 0..15
        const int p0 = pg * 4;
        float a0 = 0, a1 = 0, a2 = 0, a3 = 0;
        for (int e = 0; e < 128; ++e) {
            const float ev = enc_s[e * 33 + bI];
            const float4 h = *(const float4*)&Hf[e * 64 + p0];  // half-wave-uniform
            a0 += ev * h.x; a1 += ev * h.y; a2 += ev * h.z; a3 += ev * h.w;
        }
        vsum[(p0 + 0) * 33 + bI] = a0;
        vsum[(p0 + 1) * 33 + bI] = a1;
        vsum[(p0 + 2) * 33 + bI] = a2;
        vsum[(p0 + 3) * 33 + bI] = a3;
        __syncthreads();
    }

    // ---- chain: 10 steps, all in-block ----
    const unsigned short* Hsh = HmH;
    const unsigned short* Hsl = HmL;
    const int lanoff = rh * 2048 + half * 256 + l32 * 8;

    #pragma unroll 1
    for (int t = 1; t <= 10; ++t) {
        STAGE_ENC(t);

        // B-frags: v hi/lo split from vsum (stable since last sync)
        bfrag vbh[4], vbl[4];
        #pragma unroll
        for (int s = 0; s < 4; ++s) {
            const int p0 = s * 16 + half * 8;
            bfrag hb, lb;
            #pragma unroll
            for (int j = 0; j < 8; ++j) {
                const float f = vsum[(p0 + j) * 33 + l32];
                const unsigned short hi = bf16_rne(f);
                const unsigned short lo = bf16_rne(f - bf16_f32(hi));
                hb[j] = (short)hi;
                lb[j] = (short)lo;
            }
            vbh[s] = hb;
            vbl[s] = lb;
        }
        __syncthreads();   // enc_s staged; vsum reads complete

        // e-loop: this wave's 32-e quarter, software-pipelined (prefetch e+1)
        const unsigned short* hp = Hsh + (size_t)(eq * 32) * 4096 + lanoff;
        const unsigned short* lp = Hsl + (size_t)(eq * 32) * 4096 + lanoff;
        bfrag cah[4], cal[4];
        #pragma unroll
        for (int s = 0; s < 4; ++s) {
            cah[s] = *(const bfrag*)(hp + s * 512);
            cal[s] = *(const bfrag*)(lp + s * 512);
        }
        ffrag z = 0.0f;
        ffrag vn = 0.0f;
        #pragma unroll 2
        for (int e = 0; e < 32; ++e) {
            hp += 4096; lp += 4096;
            // prefetch next e (last iter reads <=8KB past slice: allocated ws)
            bfrag nah[4], nal[4];
            #pragma unroll
            for (int s = 0; s < 4; ++s) {
                nah[s] = *(const bfrag*)(hp + s * 512);
                nal[s] = *(const bfrag*)(lp + s * 512);
            }
            const float ev = enc_s[(eq * 32 + e) * 33 + l32];
            ffrag w = z;
            #pragma unroll
            for (int s = 0; s < 4; ++s) {
                w = __builtin_amdgcn_mfma_f32_32x32x16_bf16(cah[s], vbh[s], w, 0, 0, 0);
                w = __builtin_amdgcn_mfma_f32_32x32x16_bf16(cah[s], vbl[s], w, 0, 0, 0);
                w = __builtin_amdgcn_mfma_f32_32x32x16_bf16(cal[s], vbh[s], w, 0, 0, 0);
            }
            vn += w * ev;
            #pragma unroll
            for (int s = 0; s < 4; ++s) { cah[s] = nah[s]; cal[s] = nal[s]; }
        }
        __syncthreads();   // e-loop LDS reads done; scr region free

        // cross-eq combine in LDS (stride 66 float4)
        float4* sc4 = (float4*)scr;
        if (eq != 0) {
            const int slot = (eq - 1) * 2 + rh;
            #pragma unroll
            for (int q = 0; q < 4; ++q) {
                float4 f4 = {vn[q * 4 + 0], vn[q * 4 + 1],
                             vn[q * 4 + 2], vn[q * 4 + 3]};
                sc4[(slot * 4 + q) * 66 + lane] = f4;
            }
        }
        __syncthreads();
        if (eq == 0) {
            #pragma unroll
            for (int g = 1; g < 4; ++g) {
                const int slot = (g - 1) * 2 + rh;
                #pragma unroll
                for (int q = 0; q < 4; ++q) {
                    const float4 f4 = sc4[(slot * 4 + q) * 66 + lane];
                    vn[q * 4 + 0] += f4.x; vn[q * 4 + 1] += f4.y;
                    vn[q * 4 + 2] += f4.z; vn[q * 4 + 3] += f4.w;
                }
            }
            #pragma unroll
            for (int i = 0; i < 16; ++i) {
                const int r = rh * 32 + (i & 3) + 8 * (i >> 2) + 4 * half;
                vsum[r * 33 + l32] = vn[i];
            }
        }
        __syncthreads();   // vsum ready for next step

        Hsh += 524288;
        Hsl += 524288;
    }

    // ---- final: out[b] = sum_p v[p][b] * (sum_e enc(b,11,e) * HL[p][e]) ----
    {
        STAGE_ENC(11);
        #pragma unroll
        for (int i = 0; i < 16; ++i) {
            const int idx = i * 512 + tid;       // 8192 floats of HL [p][e]
            hl_s[(idx >> 7) * 129 + (idx & 127)] = HL[idx];
        }
        __syncthreads();
        const int bI = tid & 31, pg = tid >> 5;
        const int p0 = pg * 4;
        float s = 0.0f;
        #pragma unroll
        for (int i = 0; i < 4; ++i) {
            float L = 0.0f;
            #pragma unroll 16
            for (int e = 0; e < 128; ++e)
                L += enc_s[e * 33 + bI] * hl_s[(p0 + i) * 129 + e];
            s += vsum[(p0 + i) * 33 + bI] * L;
        }
        red[pg * 33 + bI] = s;
        __syncthreads();
        if (tid < 32) {
            float acc = 0.0f;
            #pragma unroll
            for (int g = 0; g < 16; ++g)
                acc += red[g * 33 + tid];
            out[b0 + tid] = acc;
        }
    }
    #undef STAGE_ENC
}

extern "C" void kernel_launch(void* const* d_in, const int* in_sizes, int n_in,
                              void* d_out, int out_size, void* d_ws, size_t ws_size,
                              hipStream_t stream) {
    const float* x  = (const float*)d_in[0];
    const float* W1 = (const float*)d_in[1];
    const float* b1 = (const float*)d_in[2];
    const float* W2 = (const float*)d_in[3];
    const float* b2 = (const float*)d_in[4];
    const float* Hf = (const float*)d_in[5];
    const float* Hm = (const float*)d_in[6];
    const float* HL = (const float*)d_in[7];
    float* out = (float*)d_out;
    (void)in_sizes; (void)n_in; (void)out_size; (void)ws_size;

    char* ws = (char*)d_ws;
    __half* encH        = (__half*)(ws + O_ENC);
    unsigned short* HmH = (unsigned short*)(ws + O_HMH);
    unsigned short* HmL = (unsigned short*)(ws + O_HML);
    __half* w1f         = (__half*)(ws + O_W1F);
    __half* w2f         = (__half*)(ws + O_W2F);

    prep_w<<<dim3(384), dim3(256), 0, stream>>>(W1, W2, w1f, w2f);
    enc_conv<<<dim3(2816), dim3(256), 0, stream>>>(x, b1, b2, w1f, w2f, encH,
                                                   Hm, HmH, HmL);
    chain_all<<<dim3(NBLK), dim3(512), 0, stream>>>(HmH, HmL, encH, Hf, HL, out);
}

// Round 15
// 407.666 us; speedup vs baseline: 1.2374x; 1.0012x over previous
//
#include <hip/hip_runtime.h>
#include <hip/hip_fp16.h>

// Hankel MPS, round 20: enc∥H-convert with INTERLEAVED dispatch roles.
//
// Round-14 post-mortem: enc_conv = 53+55 us exactly serialized — enc blocks
// 0..1535 fill all CUs first, conv blocks backfill only as enc drains.
// Fix: 2816 = 11 x 256; role = bid%11 (6 enc + 5 conv per group of 11) ->
// every CU holds a mix from t=0; MFMA-heavy enc overlaps BW-heavy convert.
// Both paths byte-identical; only bid->role mapping changes -> absmax
// bit-identical 1.654361e-24.
//
// chain_all: r12 form, 4x-confirmed 284.7us = per-XCD L2 fabric roofline
// (2MB/CU/step hi/lo bf16 H, irreducible at required precision).
//
// ws: encH 25.17M | HmH 10.49M | HmL 10.49M | w1f 64K | w2f 128K  (46.3 MB)

#define B_ALL 8192
#define TT    12
#define B_T   32     // trajectories per block (chain)
#define NBLK  256    // 8192 / 32

typedef short bfrag __attribute__((ext_vector_type(8)));      // 8 bf16
typedef _Float16 hfrag __attribute__((ext_vector_type(8)));   // 8 fp16
typedef float ffrag __attribute__((ext_vector_type(16)));     // 32x32 C/D

#define O_ENC   0ULL
#define O_HMH   25165824ULL
#define O_HML   35651584ULL
#define O_W1F   46137344ULL
#define O_W2F   46202880ULL

__device__ __forceinline__ unsigned short bf16_rne(float f) {
    unsigned int u = __builtin_bit_cast(unsigned int, f);
    unsigned int r = (u + 0x7fffu + ((u >> 16) & 1u)) >> 16;
    return (unsigned short)r;
}
__device__ __forceinline__ float bf16_f32(unsigned short h) {
    unsigned int u = ((unsigned int)h) << 16;
    return __builtin_bit_cast(float, u);
}

// ---------------- prep_w: W1/W2 -> fp16 frag order (tiny) ----------------
__global__ __launch_bounds__(256)
void prep_w(const float* __restrict__ W1, const float* __restrict__ W2,
            __half* __restrict__ w1f, __half* __restrict__ w2f)
{
    const int idx = blockIdx.x * 256 + threadIdx.x;
    if (idx < 32768) {
        const int w = idx;
        const int jn = w >> 11, ks = (w >> 9) & 3, half = (w >> 8) & 1;
        const int jl = (w >> 3) & 31, jj = w & 7;
        const int j = jn * 32 + jl, d = ks * 16 + half * 8 + jj;
        w1f[w] = __float2half(W1[j * 64 + d]);
    } else {
        const int w = idx - 32768;
        const int en = w >> 14, ks2g = (w >> 9) & 31, half = (w >> 8) & 1;
        const int el = (w >> 3) & 31, jj = w & 7;
        const int e = en * 32 + el, j = ks2g * 16 + half * 8 + jj;
        w2f[w] = __float2half(W2[e * 512 + j]);
    }
}

// ---------------- enc_conv: interleaved roles (6 enc + 5 conv per 11) ----------------
__global__ __launch_bounds__(256)
void enc_conv(const float* __restrict__ x,
              const float* __restrict__ b1, const float* __restrict__ b2,
              const __half* __restrict__ w1f, const __half* __restrict__ w2f,
              __half* __restrict__ encH,
              const float* __restrict__ Hm,
              unsigned short* __restrict__ Hh, unsigned short* __restrict__ Hl)
{
    __shared__ __align__(16) unsigned char smem[17408];
    const int tid = threadIdx.x;
    const int bid = blockIdx.x;
    const int grp = bid / 11;       // 0..255
    const int sl  = bid % 11;       // 0..10: 0..5 enc, 6..10 conv

    if (sl >= 6) {
        // ---- H-convert: one 64p x 64r slice (verified; index remapped) ----
        unsigned short* hs = (unsigned short*)smem;
        unsigned short* ls = (unsigned short*)(smem + 8192);
        const int hb = grp * 5 + (sl - 6);       // 0..1279
        const int t = hb >> 7, e = hb & 127;
        const float* src = Hm + ((size_t)t * 64 * 128 + e) * 64;   // + p*8192 + r
        const int p  = tid >> 2;
        const int rc = (tid & 3) * 16;
        const int fp = (p >> 4) * 512 + ((p >> 3) & 1) * 256 + (p & 7); // p part of f
        #pragma unroll
        for (int k4 = 0; k4 < 4; ++k4) {
            const int r0 = rc + k4 * 4;
            const float4 v4 = *(const float4*)&src[(size_t)p * 8192 + r0];
            const float vv[4] = {v4.x, v4.y, v4.z, v4.w};
            #pragma unroll
            for (int k = 0; k < 4; ++k) {
                const int r = r0 + k;
                const int f = (r >> 5) * 2048 + (r & 31) * 8 + fp;
                const float val = vv[k];
                const unsigned short hi = bf16_rne(val);
                const unsigned short lo = bf16_rne(val - bf16_f32(hi));
                hs[f] = hi;
                ls[f] = lo;
            }
        }
        __syncthreads();
        const size_t q0 = (size_t)t * 524288 + (size_t)e * 4096 + tid * 16;
        *(uint4*)&Hh[q0]     = *(const uint4*)&hs[tid * 16];
        *(uint4*)&Hh[q0 + 8] = *(const uint4*)&hs[tid * 16 + 8];
        *(uint4*)&Hl[q0]     = *(const uint4*)&ls[tid * 16];
        *(uint4*)&Hl[q0 + 8] = *(const uint4*)&ls[tid * 16 + 8];
        return;
    }

    // ---- enc (verbatim; m-block index remapped) ----
    float* x_s  = (float*)smem;
    __half* h_s = (__half*)smem;

    const int wv    = tid >> 6;
    const int lane  = tid & 63;
    const int l32   = lane & 31;
    const int half  = lane >> 5;
    const int msub  = wv >> 1;
    const int nhalf = wv & 1;
    const int m0    = (grp * 6 + sl) * 64;       // 0..1535 blocks of 64 rows

    #pragma unroll
    for (int i = 0; i < 4; ++i) {
        const int f4 = i * 256 + tid;
        const int r = f4 >> 4, c4 = (f4 & 15) * 4;
        *(float4*)&x_s[r * 68 + c4] =
            *(const float4*)&x[(long long)(m0 + r) * 64 + c4];
    }
    __syncthreads();

    hfrag xa[4];
    #pragma unroll
    for (int ks = 0; ks < 4; ++ks) {
        const float* src = &x_s[(msub * 32 + l32) * 68 + ks * 16 + half * 8];
        const float4 a = *(const float4*)src;
        const float4 b = *(const float4*)(src + 4);
        hfrag v;
        v[0] = (_Float16)a.x; v[1] = (_Float16)a.y;
        v[2] = (_Float16)a.z; v[3] = (_Float16)a.w;
        v[4] = (_Float16)b.x; v[5] = (_Float16)b.y;
        v[6] = (_Float16)b.z; v[7] = (_Float16)b.w;
        xa[ks] = v;
    }
    __syncthreads();

    ffrag c2[2];
    c2[0] = 0.0f; c2[1] = 0.0f;

    for (int chunk = 0; chunk < 4; ++chunk) {
        ffrag c1[2];
        float b1j[2];
        #pragma unroll
        for (int nf = 0; nf < 2; ++nf) {
            const int jn = chunk * 4 + nhalf * 2 + nf;
            b1j[nf] = b1[jn * 32 + l32];
            ffrag acc = 0.0f;
            #pragma unroll
            for (int ks = 0; ks < 4; ++ks) {
                const hfrag bh = *(const hfrag*)(w1f + (jn * 4 + ks) * 512
                                                 + half * 256 + l32 * 8);
                acc = __builtin_amdgcn_mfma_f32_32x32x16_f16(xa[ks], bh, acc, 0, 0, 0);
            }
            c1[nf] = acc;
        }
        __syncthreads();
        #pragma unroll
        for (int nf = 0; nf < 2; ++nf) {
            #pragma unroll
            for (int i2 = 0; i2 < 16; ++i2) {
                const int m_row = (i2 & 3) + 8 * (i2 >> 2) + 4 * half;
                const float v = fmaxf(c1[nf][i2] + b1j[nf], 0.0f);
                h_s[(msub * 32 + m_row) * 136 + nhalf * 64 + nf * 32 + l32] =
                    __float2half(v);
            }
        }
        __syncthreads();
        #pragma unroll
        for (int ks2 = 0; ks2 < 8; ++ks2) {
            const hfrag a = *(const hfrag*)&h_s[(msub * 32 + l32) * 136
                                                + ks2 * 16 + half * 8];
            const int ks2g = chunk * 8 + ks2;
            #pragma unroll
            for (int ef = 0; ef < 2; ++ef) {
                const int en = nhalf * 2 + ef;
                const hfrag b = *(const hfrag*)(w2f + (en * 32 + ks2g) * 512
                                                + half * 256 + l32 * 8);
                c2[ef] = __builtin_amdgcn_mfma_f32_32x32x16_f16(a, b, c2[ef], 0, 0, 0);
            }
        }
    }

    #pragma unroll
    for (int ef = 0; ef < 2; ++ef) {
        const int e = nhalf * 64 + ef * 32 + l32;
        const float b2e = b2[e];
        #pragma unroll
        for (int i2 = 0; i2 < 16; ++i2) {
            const int m_row = (i2 & 3) + 8 * (i2 >> 2) + 4 * half;
            const int m_g = m0 + msub * 32 + m_row;
            encH[(long long)m_g * 128 + e] =
                __float2half(fmaxf(c2[ef][i2] + b2e, 0.0f));
        }
    }
}

// ---------------- full chain (r12, 4x-verified 284.7us) ----------------
// 256 blocks x 512 thr (1 block/CU). Block owns b0..b0+31. 8 waves:
// eq = wv>>1 (e-quarter, 32 e), rh = wv&1 (r-half). v lives in LDS across
// all steps. e-loop software-pipelined: prefetch e+1 frags before e's MFMAs.
//
// LDS map (60480 B):
//   vsum  @ 0      : [64][33] f32                  = 8448
//   enc_s @ 8448   : [128][33] f32 (one timestep)  = 16896
//   scr   @ 25344  : stride-66 float4 combine      (chain)
//   hl_s  @ 25344  : [64][129] f32                 (final, scr dead)
//   red   @ 58368  : [16][33] f32                  (final)
__global__ __launch_bounds__(512, 1)
void chain_all(const unsigned short* __restrict__ HmH,
               const unsigned short* __restrict__ HmL,
               const __half* __restrict__ encH,
               const float* __restrict__ Hf,
               const float* __restrict__ HL,
               float* __restrict__ out)
{
    __shared__ __align__(16) unsigned char smem[60480];
    float* vsum  = (float*)smem;
    float* enc_s = (float*)(smem + 8448);
    float* scr   = (float*)(smem + 25344);
    float* hl_s  = (float*)(smem + 25344);
    float* red   = (float*)(smem + 58368);

    const int tid  = threadIdx.x;
    const int b0   = blockIdx.x * B_T;
    const int lane = tid & 63;
    const int wv   = tid >> 6;
    const int l32  = lane & 31;
    const int half = lane >> 5;
    const int eq   = wv >> 1;      // 0..3  (e-quarter)
    const int rh   = wv & 1;       // 0..1  (r-half)

    // enc staging: [128 e][32 b] f32 for one timestep (all 512 threads)
    const int sbL = tid >> 4;            // 0..31 (b-local)
    const int seo = (tid & 15) * 8;      // 0..120 (e-offset)
    #define STAGE_ENC(T)                                                      \
    {                                                                         \
        const __half* er_ = encH + ((size_t)(b0 + sbL) * 12 + (T)) * 128 + seo;\
        uint4 u = *(const uint4*)er_;                                         \
        const __half* hp_ = (const __half*)&u;                                \
        _Pragma("unroll")                                                     \
        for (int j = 0; j < 8; ++j)                                           \
            enc_s[(seo + j) * 33 + sbL] = __half2float(hp_[j]);               \
    }

    // ---- init: v0[p][b] = sum_e enc(b,0,e) * Hf[e][p] ----
    {
        STAGE_ENC(0);
        __syncthreads();
        const int bI = tid & 31, pg = tid >> 5;   // pg 0..15
        const int p0 = pg * 4;
        float a0 = 0, a1 = 0, a2 = 0, a3 = 0;
        for (int e = 0; e < 128; ++e) {
            const float ev = enc_s[e * 33 + bI];
            const float4 h = *(const float4*)&Hf[e * 64 + p0];  // half-wave-uniform
            a0 += ev * h.x; a1 += ev * h.y; a2 += ev * h.z; a3 += ev * h.w;
        }
        vsum[(p0 + 0) * 33 + bI] = a0;
        vsum[(p0 + 1) * 33 + bI] = a1;
        vsum[(p0 + 2) * 33 + bI] = a2;
        vsum[(p0 + 3) * 33 + bI] = a3;
        __syncthreads();
    }

    // ---- chain: 10 steps, all in-block ----
    const unsigned short* Hsh = HmH;
    const unsigned short* Hsl = HmL;
    const int lanoff = rh * 2048 + half * 256 + l32 * 8;

    #pragma unroll 1
    for (int t = 1; t <= 10; ++t) {
        STAGE_ENC(t);

        // B-frags: v hi/lo split from vsum (stable since last sync)
        bfrag vbh[4], vbl[4];
        #pragma unroll
        for (int s = 0; s < 4; ++s) {
            const int p0 = s * 16 + half * 8;
            bfrag hb, lb;
            #pragma unroll
            for (int j = 0; j < 8; ++j) {
                const float f = vsum[(p0 + j) * 33 + l32];
                const unsigned short hi = bf16_rne(f);
                const unsigned short lo = bf16_rne(f - bf16_f32(hi));
                hb[j] = (short)hi;
                lb[j] = (short)lo;
            }
            vbh[s] = hb;
            vbl[s] = lb;
        }
        __syncthreads();   // enc_s staged; vsum reads complete

        // e-loop: this wave's 32-e quarter, software-pipelined (prefetch e+1)
        const unsigned short* hp = Hsh + (size_t)(eq * 32) * 4096 + lanoff;
        const unsigned short* lp = Hsl + (size_t)(eq * 32) * 4096 + lanoff;
        bfrag cah[4], cal[4];
        #pragma unroll
        for (int s = 0; s < 4; ++s) {
            cah[s] = *(const bfrag*)(hp + s * 512);
            cal[s] = *(const bfrag*)(lp + s * 512);
        }
        ffrag z = 0.0f;
        ffrag vn = 0.0f;
        #pragma unroll 2
        for (int e = 0; e < 32; ++e) {
            hp += 4096; lp += 4096;
            // prefetch next e (last iter reads <=8KB past slice: allocated ws)
            bfrag nah[4], nal[4];
            #pragma unroll
            for (int s = 0; s < 4; ++s) {
                nah[s] = *(const bfrag*)(hp + s * 512);
                nal[s] = *(const bfrag*)(lp + s * 512);
            }
            const float ev = enc_s[(eq * 32 + e) * 33 + l32];
            ffrag w = z;
            #pragma unroll
            for (int s = 0; s < 4; ++s) {
                w = __builtin_amdgcn_mfma_f32_32x32x16_bf16(cah[s], vbh[s], w, 0, 0, 0);
                w = __builtin_amdgcn_mfma_f32_32x32x16_bf16(cah[s], vbl[s], w, 0, 0, 0);
                w = __builtin_amdgcn_mfma_f32_32x32x16_bf16(cal[s], vbh[s], w, 0, 0, 0);
            }
            vn += w * ev;
            #pragma unroll
            for (int s = 0; s < 4; ++s) { cah[s] = nah[s]; cal[s] = nal[s]; }
        }
        __syncthreads();   // e-loop LDS reads done; scr region free

        // cross-eq combine in LDS (stride 66 float4)
        float4* sc4 = (float4*)scr;
        if (eq != 0) {
            const int slot = (eq - 1) * 2 + rh;
            #pragma unroll
            for (int q = 0; q < 4; ++q) {
                float4 f4 = {vn[q * 4 + 0], vn[q * 4 + 1],
                             vn[q * 4 + 2], vn[q * 4 + 3]};
                sc4[(slot * 4 + q) * 66 + lane] = f4;
            }
        }
        __syncthreads();
        if (eq == 0) {
            #pragma unroll
            for (int g = 1; g < 4; ++g) {
                const int slot = (g - 1) * 2 + rh;
                #pragma unroll
                for (int q = 0; q < 4; ++q) {
                    const float4 f4 = sc4[(slot * 4 + q) * 66 + lane];
                    vn[q * 4 + 0] += f4.x; vn[q * 4 + 1] += f4.y;
                    vn[q * 4 + 2] += f4.z; vn[q * 4 + 3] += f4.w;
                }
            }
            #pragma unroll
            for (int i = 0; i < 16; ++i) {
                const int r = rh * 32 + (i & 3) + 8 * (i >> 2) + 4 * half;
                vsum[r * 33 + l32] = vn[i];
            }
        }
        __syncthreads();   // vsum ready for next step

        Hsh += 524288;
        Hsl += 524288;
    }

    // ---- final: out[b] = sum_p v[p][b] * (sum_e enc(b,11,e) * HL[p][e]) ----
    {
        STAGE_ENC(11);
        #pragma unroll
        for (int i = 0; i < 16; ++i) {
            const int idx = i * 512 + tid;       // 8192 floats of HL [p][e]
            hl_s[(idx >> 7) * 129 + (idx & 127)] = HL[idx];
        }
        __syncthreads();
        const int bI = tid & 31, pg = tid >> 5;
        const int p0 = pg * 4;
        float s = 0.0f;
        #pragma unroll
        for (int i = 0; i < 4; ++i) {
            float L = 0.0f;
            #pragma unroll 16
            for (int e = 0; e < 128; ++e)
                L += enc_s[e * 33 + bI] * hl_s[(p0 + i) * 129 + e];
            s += vsum[(p0 + i) * 33 + bI] * L;
        }
        red[pg * 33 + bI] = s;
        __syncthreads();
        if (tid < 32) {
            float acc = 0.0f;
            #pragma unroll
            for (int g = 0; g < 16; ++g)
                acc += red[g * 33 + tid];
            out[b0 + tid] = acc;
        }
    }
    #undef STAGE_ENC
}

extern "C" void kernel_launch(void* const* d_in, const int* in_sizes, int n_in,
                              void* d_out, int out_size, void* d_ws, size_t ws_size,
                              hipStream_t stream) {
    const float* x  = (const float*)d_in[0];
    const float* W1 = (const float*)d_in[1];
    const float* b1 = (const float*)d_in[2];
    const float* W2 = (const float*)d_in[3];
    const float* b2 = (const float*)d_in[4];
    const float* Hf = (const float*)d_in[5];
    const float* Hm = (const float*)d_in[6];
    const float* HL = (const float*)d_in[7];
    float* out = (float*)d_out;
    (void)in_sizes; (void)n_in; (void)out_size; (void)ws_size;

    char* ws = (char*)d_ws;
    __half* encH        = (__half*)(ws + O_ENC);
    unsigned short* HmH = (unsigned short*)(ws + O_HMH);
    unsigned short* HmL = (unsigned short*)(ws + O_HML);
    __half* w1f         = (__half*)(ws + O_W1F);
    __half* w2f         = (__half*)(ws + O_W2F);

    prep_w<<<dim3(384), dim3(256), 0, stream>>>(W1, W2, w1f, w2f);
    enc_conv<<<dim3(2816), dim3(256), 0, stream>>>(x, b1, b2, w1f, w2f, encH,
                                                   Hm, HmH, HmL);
    chain_all<<<dim3(NBLK), dim3(512), 0, stream>>>(HmH, HmL, encH, Hf, HL, out);
}